// Round 9
// baseline (758.818 us; speedup 1.0000x reference)
//
#include <hip/hip_runtime.h>
#include <hip/hip_bf16.h>
#include <math.h>

typedef unsigned short ushort_t;
typedef short short8 __attribute__((ext_vector_type(8)));
typedef float f32x4 __attribute__((ext_vector_type(4)));

#define E_TOTAL 400000
#define ET 64          // edges per block
#define NTHR 512       // 8 waves
#define NODE_D 120
#define ASTR 36        // fp32 a-part LDS stride (2-way bank alias: free)
#define BSTR 48        // fp32 b-part LDS stride
#define CSTR 44        // fp32 c-part LDS stride

#define ALPHA 0.0272772362793f   // 1/sqrt(1344)
#define S_L1  0.57735026918962f  // 1/sqrt(3)
#define S_L2  0.44721359549996f  // 1/sqrt(5)

// ws layout (ushort elements): TP W-frags [0,172032), df_w1 [172032,180224),
// df_w2 [180224,196608), mlp_w1 [196608,262144).  B-frag order:
// idx = ((kt*NT + nt)*64 + lane)*8 + jj  with k = kt*32 + 8*(lane>>4) + jj,
// n = nt*16 + (lane&15).
#define WS_WF1 172032
#define WS_WF2 180224
#define WS_WM1 196608
#define WS_TOTAL 262144

__device__ __forceinline__ ushort_t f2b(float f) {
    unsigned int b = __float_as_uint(f);
    b += 0x7FFFu + ((b >> 16) & 1u);   // RNE
    return (ushort_t)(b >> 16);
}
__device__ __forceinline__ unsigned int f2b2(float a, float b) {
    __hip_bfloat162 h = __float22bfloat162_rn(make_float2(a, b));  // v_cvt_pk_bf16_f32
    union { __hip_bfloat162 h2; unsigned int u; } cv; cv.h2 = h;
    return cv.u;
}
__device__ __forceinline__ float silu_f(float x) { return x / (1.0f + __expf(-x)); }

__global__ __launch_bounds__(256) void prep_weights(
    const float* __restrict__ W0, const float* __restrict__ W1, const float* __restrict__ W2,
    const float* __restrict__ df_w1, const float* __restrict__ df_w2,
    const float* __restrict__ mlp_w1, ushort_t* __restrict__ ws)
{
    const int i = blockIdx.x * 256 + threadIdx.x;
    if (i >= WS_TOTAL) return;
    float v;
    if (i < WS_WF1) {            // TP: 42 kt x 8 nt
        const int r = i;
        const int kt = r >> 12, nt = (r >> 9) & 7, l = (r >> 3) & 63, jj = r & 7;
        const int k = kt * 32 + ((l >> 4) << 3) + jj;
        const int n = nt * 16 + (l & 15);
        if (k < 1024)      v = W0[k * 128 + n] * ALPHA;
        else if (k < 1280) v = W1[(k - 1024) * 128 + n] * (ALPHA * S_L1);
        else               v = W2[(k - 1280) * 128 + n] * (ALPHA * S_L2);
    } else if (i < WS_WF2) {     // df_w1: 2 kt x 8 nt
        const int r = i - WS_WF1;
        const int kt = r >> 12, nt = (r >> 9) & 7, l = (r >> 3) & 63, jj = r & 7;
        v = df_w1[(kt * 32 + ((l >> 4) << 3) + jj) * 128 + nt * 16 + (l & 15)];
    } else if (i < WS_WM1) {     // df_w2: 4 kt x 8 nt
        const int r = i - WS_WF2;
        const int kt = r >> 12, nt = (r >> 9) & 7, l = (r >> 3) & 63, jj = r & 7;
        v = df_w2[(kt * 32 + ((l >> 4) << 3) + jj) * 128 + nt * 16 + (l & 15)];
    } else {                     // mlp_w1: 4 kt x 32 nt
        const int r = i - WS_WM1;
        const int kt = r >> 14, nt = (r >> 9) & 31, l = (r >> 3) & 63, jj = r & 7;
        v = mlp_w1[(kt * 32 + ((l >> 4) << 3) + jj) * 512 + nt * 16 + (l & 15)];
    }
    ws[i] = f2b(v);
}

__global__ __launch_bounds__(NTHR, 3) void fused_edge_kernel(
    const float* __restrict__ nodes, const int* __restrict__ edge_index,
    const int* __restrict__ graph_batch, const float* __restrict__ cell,
    const float* __restrict__ edge_shift, const float* __restrict__ pos,
    const float* __restrict__ ln_g, const float* __restrict__ ln_b,
    const float* __restrict__ df_b1, const float* __restrict__ df_b2,
    const float* __restrict__ mlp_b1, const float* __restrict__ mlp_w2,
    const float* __restrict__ mlp_b2,
    const ushort_t* __restrict__ wsp, float* __restrict__ out)
{
    // Arena 40960 B, time-multiplexed:
    //  [0,16384)      Pf 4-kt A-frag chunks (TP) -> dembF [0,8192) -> regF [0,16384)
    //  [16384,40960)  xa1/xa2 (l0) -> b1s/b2s (l1) -> c1s/c2s (l2)
    //                 -> h1F [16384,32768) + red1 [32768,36864) + red2 [36864,38912)
    __shared__ __align__(16) char Ar[40960];
    __shared__ float dist_s[ET];
    __shared__ int sidx[ET], didx[ET];
    __shared__ float mu_s[ET], rstd_s[ET];

    ushort_t* Pf    = (ushort_t*)Ar;
    ushort_t* dembF = (ushort_t*)Ar;
    ushort_t* regF  = (ushort_t*)Ar;
    float* xa1 = (float*)(Ar + 16384);
    float* xa2 = (float*)(Ar + 25600);
    float* b1s = (float*)(Ar + 16384);
    float* b2s = (float*)(Ar + 28672);
    float* c1s = (float*)(Ar + 16384);
    float* c2s = (float*)(Ar + 27648);
    ushort_t* h1F = (ushort_t*)(Ar + 16384);
    float* red1 = (float*)(Ar + 32768);
    float* red2 = (float*)(Ar + 36864);

    const int tid = threadIdx.x;
    const int e0g = blockIdx.x * ET;
    const int wave = tid >> 6, lane = tid & 63;
    const int lr = lane & 15, lg = lane >> 4;
    const int er = lane & 15, kg = lane >> 4;   // A-fragment coords
    const int w = wave;
    const int ktl0 = w >> 1;          // owned local k-tile for l0/l1 builds
    const int hb = (w & 1) * 2;       // h-pair base for this wave's slots

    // ---- phase 0: geometry ----
    if (tid < ET) {
        const int e = e0g + tid;
        const int s = edge_index[e];
        const int d = edge_index[E_TOTAL + e];
        sidx[tid] = s; didx[tid] = d;
        const int g = graph_batch[s];
        const float* c = cell + g * 9;
        const float sx = edge_shift[e * 3], sy = edge_shift[e * 3 + 1], sz = edge_shift[e * 3 + 2];
        const float t0 = sx * c[0] + sy * c[3] + sz * c[6];
        const float t1 = sx * c[1] + sy * c[4] + sz * c[7];
        const float t2 = sx * c[2] + sy * c[5] + sz * c[8];
        const float r0 = pos[d * 3 + 0] - pos[s * 3 + 0] + t0;
        const float r1 = pos[d * 3 + 1] - pos[s * 3 + 1] + t1;
        const float r2 = pos[d * 3 + 2] - pos[s * 3 + 2] + t2;
        dist_s[tid] = sqrtf(r0 * r0 + r1 * r1 + r2 * r2);
    }
    __syncthreads();

    // ---- gather a-parts (first 32 floats of each node row) ----
    {
        const int e = tid >> 3, c = tid & 7;   // exactly 512 slots
        *(float4*)(xa1 + e * ASTR + c * 4) = *(const float4*)(nodes + (size_t)sidx[e] * NODE_D + c * 4);
        *(float4*)(xa2 + e * ASTR + c * 4) = *(const float4*)(nodes + (size_t)didx[e] * NODE_D + c * 4);
    }
    __syncthreads();

    const char* pA = (const char*)Pf + lane * 16;
    const short8* WT8 = (const short8*)wsp;
    const int bcol = tid;   // wave*64 + lane; wave == n-tile

    f32x4 acc[4] = {{0.f,0.f,0.f,0.f},{0.f,0.f,0.f,0.f},{0.f,0.f,0.f,0.f},{0.f,0.f,0.f,0.f}};

    // hoist a2 for this thread's two h rows (16 floats)
    float2 a2v[2][4];
#pragma unroll
    for (int hh = 0; hh < 2; ++hh)
#pragma unroll
        for (int q = 0; q < 4; ++q)
            a2v[hh][q] = *(const float2*)(xa2 + ((hb + hh) * 16 + er) * ASTR + kg * 8 + q * 2);

    // ---- TP l0: 8 chunks of 4 k-tiles (K = 8 x 128) ----
#pragma unroll 1
    for (int c4 = 0; c4 < 8; ++c4) {
#pragma unroll
        for (int hh = 0; hh < 2; ++hh) {
            const int h = hb + hh;
            const float a1 = xa1[(h * 16 + er) * ASTR + c4 * 4 + ktl0];
            uint4 o;
            o.x = f2b2(a1 * a2v[hh][0].x, a1 * a2v[hh][0].y);
            o.y = f2b2(a1 * a2v[hh][1].x, a1 * a2v[hh][1].y);
            o.z = f2b2(a1 * a2v[hh][2].x, a1 * a2v[hh][2].y);
            o.w = f2b2(a1 * a2v[hh][3].x, a1 * a2v[hh][3].y);
            *(uint4*)(Pf + ((ktl0 * 4 + h) * 64 + lane) * 8) = o;
        }
        __syncthreads();
#pragma unroll
        for (int kt = 0; kt < 4; ++kt) {
            const short8 b = WT8[(c4 * 4 + kt) * 512 + bcol];
#pragma unroll
            for (int h = 0; h < 4; ++h) {
                const short8 a = *(const short8*)(pA + (kt * 4 + h) * 1024);
                acc[h] = __builtin_amdgcn_mfma_f32_16x16x32_bf16(a, b, acc[h], 0, 0, 0);
            }
        }
        __syncthreads();
    }

    // ---- gather b-parts (floats 32..79); xa dead ----
    for (int i = tid; i < ET * 16; i += NTHR) {
        const int e = i >> 4, c = i & 15;
        if (c < 12) {
            *(float4*)(b1s + e * BSTR + c * 4) =
                *(const float4*)(nodes + (size_t)sidx[e] * NODE_D + 32 + c * 4);
            *(float4*)(b2s + e * BSTR + c * 4) =
                *(const float4*)(nodes + (size_t)didx[e] * NODE_D + 32 + c * 4);
        }
    }
    __syncthreads();

    // ---- TP l1: 2 chunks of 4 k-tiles (K = 2 x 128) ----
#pragma unroll 1
    for (int cc = 0; cc < 2; ++cc) {
#pragma unroll
        for (int hh = 0; hh < 2; ++hh) {
            const int h = hb + hh;
            const int e = h * 16 + er;
            const int u1 = 2 * (cc * 4 + ktl0) + (kg >> 1);
            const float* b1p = b1s + e * BSTR + 3 * u1;
            const float ba = b1p[0], bbv = b1p[1], bcv = b1p[2];
            const float* b2p = b2s + e * BSTR + 3 * ((kg & 1) * 8);
            float pr[8];
#pragma unroll
            for (int jj = 0; jj < 8; ++jj)
                pr[jj] = ba * b2p[3 * jj] + bbv * b2p[3 * jj + 1] + bcv * b2p[3 * jj + 2];
            uint4 o;
            o.x = f2b2(pr[0], pr[1]); o.y = f2b2(pr[2], pr[3]);
            o.z = f2b2(pr[4], pr[5]); o.w = f2b2(pr[6], pr[7]);
            *(uint4*)(Pf + ((ktl0 * 4 + h) * 64 + lane) * 8) = o;
        }
        __syncthreads();
#pragma unroll
        for (int kt = 0; kt < 4; ++kt) {
            const short8 b = WT8[(32 + cc * 4 + kt) * 512 + bcol];
#pragma unroll
            for (int h = 0; h < 4; ++h) {
                const short8 a = *(const short8*)(pA + (kt * 4 + h) * 1024);
                acc[h] = __builtin_amdgcn_mfma_f32_16x16x32_bf16(a, b, acc[h], 0, 0, 0);
            }
        }
        __syncthreads();
    }

    // ---- gather c-parts (floats 80..119); b dead ----
    for (int i = tid; i < ET * 16; i += NTHR) {
        const int e = i >> 4, c = i & 15;
        if (c < 10) {
            *(float4*)(c1s + e * CSTR + c * 4) =
                *(const float4*)(nodes + (size_t)sidx[e] * NODE_D + 80 + c * 4);
            *(float4*)(c2s + e * CSTR + c * 4) =
                *(const float4*)(nodes + (size_t)didx[e] * NODE_D + 80 + c * 4);
        }
    }
    __syncthreads();

    // ---- TP l2: 2 k-tiles; wave w owns slot (ktl = w>>2, h = w&3) ----
    {
        const int ktl = w >> 2, h2 = w & 3;
        const int u2 = ktl * 4 + kg;
        const int e = h2 * 16 + er;
        const float* c1p = c1s + e * CSTR + 5 * u2;
        const float ca = c1p[0], cb = c1p[1], cc2 = c1p[2], cd = c1p[3], ce = c1p[4];
        float pr[8];
#pragma unroll
        for (int jj = 0; jj < 8; ++jj) {
            const float* c2p = c2s + e * CSTR + 5 * jj;
            pr[jj] = ca * c2p[0] + cb * c2p[1] + cc2 * c2p[2] + cd * c2p[3] + ce * c2p[4];
        }
        uint4 o;
        o.x = f2b2(pr[0], pr[1]); o.y = f2b2(pr[2], pr[3]);
        o.z = f2b2(pr[4], pr[5]); o.w = f2b2(pr[6], pr[7]);
        *(uint4*)(Pf + ((ktl * 4 + h2) * 64 + lane) * 8) = o;
    }
    __syncthreads();
#pragma unroll
    for (int kt = 0; kt < 2; ++kt) {
        const short8 b = WT8[(40 + kt) * 512 + bcol];
#pragma unroll
        for (int h = 0; h < 4; ++h) {
            const short8 a = *(const short8*)(pA + (kt * 4 + h) * 1024);
            acc[h] = __builtin_amdgcn_mfma_f32_16x16x32_bf16(a, b, acc[h], 0, 0, 0);
        }
    }
    __syncthreads();   // Pf dead -> dembF region free

    // ---- demb build (fragment-linear, into Pf region) ----
    for (int i = tid; i < ET * 64; i += NTHR) {
        const int e = i >> 6, k = i & 63;
        const float d = dist_s[e];
        const float t = d - (7.0f / 63.0f) * (float)k;
        const float rbf = __expf(-40.5f * t * t);
        const float env = (d < 7.0f) ? (0.5f * (__cosf(d * (3.14159265358979f / 7.0f)) + 1.0f)) : 0.0f;
        const int ktl = k >> 5, kgd = (k >> 3) & 3, jj = k & 7, half = e >> 4, row = e & 15;
        dembF[((ktl * 4 + half) * 64 + kgd * 16 + row) * 8 + jj] = f2b(rbf * env);
    }
    __syncthreads();

    // ---- filter GEMM1: h1 = silu(demb @ df_w1 + b1) -> h1F (c region dead) ----
    {
        f32x4 f[4] = {{0.f,0.f,0.f,0.f},{0.f,0.f,0.f,0.f},{0.f,0.f,0.f,0.f},{0.f,0.f,0.f,0.f}};
        const char* dA = (const char*)dembF + lane * 16;
#pragma unroll
        for (int kt = 0; kt < 2; ++kt) {
            const short8 b = WT8[WS_WF1 / 8 + kt * 512 + bcol];
#pragma unroll
            for (int h = 0; h < 4; ++h) {
                const short8 a = *(const short8*)(dA + (kt * 4 + h) * 1024);
                f[h] = __builtin_amdgcn_mfma_f32_16x16x32_bf16(a, b, f[h], 0, 0, 0);
            }
        }
        const int n = wave * 16 + lr;
        const float bb = df_b1[n];
        const int ktl = n >> 5, kg2 = (n >> 3) & 3, jjn = n & 7;
#pragma unroll
        for (int h = 0; h < 4; ++h)
#pragma unroll
            for (int r = 0; r < 4; ++r)
                h1F[((ktl * 4 + h) * 64 + kg2 * 16 + lg * 4 + r) * 8 + jjn] = f2b(silu_f(f[h][r] + bb));
    }
    __syncthreads();

    // ---- filter GEMM2 -> dfilter regs + LN partials ----
    f32x4 d[4] = {{0.f,0.f,0.f,0.f},{0.f,0.f,0.f,0.f},{0.f,0.f,0.f,0.f},{0.f,0.f,0.f,0.f}};
    {
        const char* hA = (const char*)h1F + lane * 16;
#pragma unroll
        for (int kt = 0; kt < 4; ++kt) {
            const short8 b = WT8[WS_WF2 / 8 + kt * 512 + bcol];
#pragma unroll
            for (int h = 0; h < 4; ++h) {
                const short8 a = *(const short8*)(hA + (kt * 4 + h) * 1024);
                d[h] = __builtin_amdgcn_mfma_f32_16x16x32_bf16(a, b, d[h], 0, 0, 0);
            }
        }
        const int n = wave * 16 + lr;
        const float b2v = df_b2[n];
#pragma unroll
        for (int h = 0; h < 4; ++h)
#pragma unroll
            for (int r = 0; r < 4; ++r) d[h][r] += b2v;
    }
#pragma unroll
    for (int h = 0; h < 4; ++h) {
#pragma unroll
        for (int r = 0; r < 4; ++r) {
            const float v = acc[h][r];
            float s1 = v, s2 = v * v;
            s1 += __shfl_xor(s1, 1);  s2 += __shfl_xor(s2, 1);
            s1 += __shfl_xor(s1, 2);  s2 += __shfl_xor(s2, 2);
            s1 += __shfl_xor(s1, 4);  s2 += __shfl_xor(s2, 4);
            s1 += __shfl_xor(s1, 8);  s2 += __shfl_xor(s2, 8);
            if (lr == 0) {
                const int idx = ((wave * 4 + h) * 4 + lg) * 4 + r;
                red1[idx] = s1;
                red1[512 + idx] = s2;
            }
        }
    }
    __syncthreads();
    if (tid < ET) {
        const int h = tid >> 4, g = (tid >> 2) & 3, r = tid & 3;
        float s1 = 0.f, s2 = 0.f;
#pragma unroll
        for (int ww = 0; ww < 8; ++ww) {
            const int idx = ((ww * 4 + h) * 4 + g) * 4 + r;
            s1 += red1[idx];
            s2 += red1[512 + idx];
        }
        const float mu = s1 * (1.0f / 128.0f);
        const float var = s2 * (1.0f / 128.0f) - mu * mu;
        mu_s[tid] = mu;
        rstd_s[tid] = rsqrtf(var + 1e-5f);
    }
    __syncthreads();

    // ---- regulated -> regF (fragment-linear bf16, into Pf region; dembF dead) ----
    {
        const int n = wave * 16 + lr;
        const float gv = ln_g[n], bv = ln_b[n];
        const int ktl = n >> 5, kg2 = (n >> 3) & 3, jjn = n & 7;
#pragma unroll
        for (int h = 0; h < 4; ++h) {
#pragma unroll
            for (int r = 0; r < 4; ++r) {
                const int row = lg * 4 + r, e = h * 16 + row;
                const float ln = (acc[h][r] - mu_s[e]) * rstd_s[e] * gv + bv;
                regF[((ktl * 4 + h) * 64 + kg2 * 16 + row) * 8 + jjn] = f2b(ln * d[h][r]);
            }
        }
    }
    __syncthreads();

    // ---- MLP: out = silu(reg @ w1 + b1) @ w2 + b2  (two q-passes) ----
    {
        float po[4][4];
#pragma unroll
        for (int h = 0; h < 4; ++h)
#pragma unroll
            for (int r = 0; r < 4; ++r) po[h][r] = 0.f;
        const char* rA = (const char*)regF + lane * 16;
#pragma unroll 1
        for (int qp = 0; qp < 2; ++qp) {
            f32x4 m[2][4];
#pragma unroll
            for (int qq = 0; qq < 2; ++qq)
#pragma unroll
                for (int h = 0; h < 4; ++h) m[qq][h] = (f32x4){0.f,0.f,0.f,0.f};
#pragma unroll
            for (int kt = 0; kt < 4; ++kt) {
                short8 a[4];
#pragma unroll
                for (int h = 0; h < 4; ++h)
                    a[h] = *(const short8*)(rA + (kt * 4 + h) * 1024);
                const int base = WS_WM1 / 8 + kt * 2048 + wave * 256 + lane + qp * 128;
#pragma unroll
                for (int qq = 0; qq < 2; ++qq) {
                    const short8 b = WT8[base + qq * 64];
#pragma unroll
                    for (int h = 0; h < 4; ++h)
                        m[qq][h] = __builtin_amdgcn_mfma_f32_16x16x32_bf16(a[h], b, m[qq][h], 0, 0, 0);
                }
            }
#pragma unroll
            for (int qq = 0; qq < 2; ++qq) {
                const int n = (wave * 4 + qp * 2 + qq) * 16 + lr;
                const float b1v = mlp_b1[n];
                const float w2v = mlp_w2[n];
#pragma unroll
                for (int h = 0; h < 4; ++h)
#pragma unroll
                    for (int r = 0; r < 4; ++r)
                        po[h][r] += silu_f(m[qq][h][r] + b1v) * w2v;
            }
        }
#pragma unroll
        for (int h = 0; h < 4; ++h) {
#pragma unroll
            for (int r = 0; r < 4; ++r) {
                float a = po[h][r];
                a += __shfl_xor(a, 1);
                a += __shfl_xor(a, 2);
                a += __shfl_xor(a, 4);
                a += __shfl_xor(a, 8);
                if (lr == 0) red2[((wave * 4 + h) * 4 + lg) * 4 + r] = a;
            }
        }
    }
    __syncthreads();
    if (tid < ET) {
        const int h = tid >> 4, g = (tid >> 2) & 3, r = tid & 3;
        float s = 0.f;
#pragma unroll
        for (int ww = 0; ww < 8; ++ww)
            s += red2[((ww * 4 + h) * 4 + g) * 4 + r];
        out[e0g + tid] = s + mlp_b2[0];
    }
}

extern "C" void kernel_launch(void* const* d_in, const int* in_sizes, int n_in,
                              void* d_out, int out_size, void* d_ws, size_t ws_size,
                              hipStream_t stream) {
    const float* nodes      = (const float*)d_in[0];
    const int*   edge_index = (const int*)  d_in[1];
    const int*   graph_b    = (const int*)  d_in[2];
    const float* cell       = (const float*)d_in[3];
    const float* edge_shift = (const float*)d_in[4];
    const float* pos        = (const float*)d_in[5];
    const float* W0         = (const float*)d_in[6];
    const float* W1         = (const float*)d_in[7];
    const float* W2         = (const float*)d_in[8];
    const float* ln_g       = (const float*)d_in[9];
    const float* ln_b       = (const float*)d_in[10];
    const float* df_w1      = (const float*)d_in[11];
    const float* df_b1      = (const float*)d_in[12];
    const float* df_w2      = (const float*)d_in[13];
    const float* df_b2      = (const float*)d_in[14];
    const float* mlp_w1     = (const float*)d_in[15];
    const float* mlp_b1     = (const float*)d_in[16];
    const float* mlp_w2     = (const float*)d_in[17];
    const float* mlp_b2     = (const float*)d_in[18];
    float* out = (float*)d_out;
    ushort_t* ws = (ushort_t*)d_ws;

    hipLaunchKernelGGL(prep_weights, dim3((WS_TOTAL + 255) / 256), dim3(256), 0, stream,
                       W0, W1, W2, df_w1, df_w2, mlp_w1, ws);

    const int E = in_sizes[1] / 2;
    const int grid = E / ET;   // 6250
    hipLaunchKernelGGL(fused_edge_kernel, dim3(grid), dim3(NTHR), 0, stream,
                       nodes, edge_index, graph_b, cell, edge_shift, pos,
                       ln_g, ln_b, df_b1, df_b2, mlp_b1, mlp_w2, mlp_b2,
                       ws, out);
}

// Round 11
// 568.911 us; speedup vs baseline: 1.3338x; 1.3338x over previous
//
#include <hip/hip_runtime.h>
#include <hip/hip_bf16.h>
#include <math.h>

typedef unsigned short ushort_t;
typedef short short8 __attribute__((ext_vector_type(8)));
typedef float f32x4 __attribute__((ext_vector_type(4)));

#define E_TOTAL 400000
#define ET 64          // edges per block
#define NTHR 512       // 8 waves
#define NODE_D 120
#define ASTR 36
#define BSTR 48
#define CSTR 44

#define ALPHA 0.0272772362793f   // 1/sqrt(1344)
#define S_L1  0.57735026918962f  // 1/sqrt(3)
#define S_L2  0.44721359549996f  // 1/sqrt(5)

#define WS_WF1 172032
#define WS_WF2 180224
#define WS_WM1 196608
#define WS_TOTAL 262144

__device__ __forceinline__ ushort_t f2b(float f) {
    unsigned int b = __float_as_uint(f);
    b += 0x7FFFu + ((b >> 16) & 1u);   // RNE
    return (ushort_t)(b >> 16);
}
__device__ __forceinline__ unsigned int f2b2(float a, float b) {
    __hip_bfloat162 h = __float22bfloat162_rn(make_float2(a, b));  // v_cvt_pk_bf16_f32
    union { __hip_bfloat162 h2; unsigned int u; } cv; cv.h2 = h;
    return cv.u;
}
__device__ __forceinline__ float silu_f(float x) { return x / (1.0f + __expf(-x)); }

__global__ __launch_bounds__(256) void prep_weights(
    const float* __restrict__ W0, const float* __restrict__ W1, const float* __restrict__ W2,
    const float* __restrict__ df_w1, const float* __restrict__ df_w2,
    const float* __restrict__ mlp_w1, ushort_t* __restrict__ ws)
{
    const int i = blockIdx.x * 256 + threadIdx.x;
    if (i >= WS_TOTAL) return;
    float v;
    if (i < WS_WF1) {            // TP: 42 kt x 8 nt
        const int r = i;
        const int kt = r >> 12, nt = (r >> 9) & 7, l = (r >> 3) & 63, jj = r & 7;
        const int k = kt * 32 + ((l >> 4) << 3) + jj;
        const int n = nt * 16 + (l & 15);
        if (k < 1024)      v = W0[k * 128 + n] * ALPHA;
        else if (k < 1280) v = W1[(k - 1024) * 128 + n] * (ALPHA * S_L1);
        else               v = W2[(k - 1280) * 128 + n] * (ALPHA * S_L2);
    } else if (i < WS_WF2) {     // df_w1
        const int r = i - WS_WF1;
        const int kt = r >> 12, nt = (r >> 9) & 7, l = (r >> 3) & 63, jj = r & 7;
        v = df_w1[(kt * 32 + ((l >> 4) << 3) + jj) * 128 + nt * 16 + (l & 15)];
    } else if (i < WS_WM1) {     // df_w2
        const int r = i - WS_WF2;
        const int kt = r >> 12, nt = (r >> 9) & 7, l = (r >> 3) & 63, jj = r & 7;
        v = df_w2[(kt * 32 + ((l >> 4) << 3) + jj) * 128 + nt * 16 + (l & 15)];
    } else {                     // mlp_w1
        const int r = i - WS_WM1;
        const int kt = r >> 14, nt = (r >> 9) & 31, l = (r >> 3) & 63, jj = r & 7;
        v = mlp_w1[(kt * 32 + ((l >> 4) << 3) + jj) * 512 + nt * 16 + (l & 15)];
    }
    ws[i] = f2b(v);
}

__global__ __launch_bounds__(NTHR, 4) void fused_edge_kernel(
    const float* __restrict__ nodes, const int* __restrict__ edge_index,
    const int* __restrict__ graph_batch, const float* __restrict__ cell,
    const float* __restrict__ edge_shift, const float* __restrict__ pos,
    const float* __restrict__ ln_g, const float* __restrict__ ln_b,
    const float* __restrict__ df_b1, const float* __restrict__ df_b2,
    const float* __restrict__ mlp_b1, const float* __restrict__ mlp_w2,
    const float* __restrict__ mlp_b2,
    const ushort_t* __restrict__ wsp, float* __restrict__ out)
{
    // Pf: two 16 KB A-fragment buffers (4 kt x 4 h x 64 lanes x 8 us each).
    __shared__ __align__(16) ushort_t Pf[16384];
    // Xb arena (43008 B):
    //  xa1 [0,9216) xa2 [9216,18432)          (l0 operands)
    //  b1s [18432,30720) b2s [30720,43008)    (l1 operands; NO alias with xa)
    //  c1s [0,11264) c2s [11264,22528)        (l2; aliases xa + b1s head ->
    //                                          c-gather MUST be after last b read)
    //  post-TP: h1F [0,16384) regF [16384,32768) red1 [32768,36864) red2 [36864,38912)
    __shared__ __align__(16) char Xb[43008];
    __shared__ float dist_s[ET];
    __shared__ int sidx[ET], didx[ET];
    __shared__ float mu_s[ET], rstd_s[ET];

    float* xa1 = (float*)Xb;
    float* xa2 = (float*)(Xb + 9216);
    float* b1s = (float*)(Xb + 18432);
    float* b2s = (float*)(Xb + 30720);
    float* c1s = (float*)Xb;
    float* c2s = (float*)(Xb + 11264);
    ushort_t* h1F  = (ushort_t*)Xb;
    ushort_t* regF = (ushort_t*)(Xb + 16384);
    float* red1 = (float*)(Xb + 32768);
    float* red2 = (float*)(Xb + 36864);
    ushort_t* dembF = Pf + 8192;   // buf1 region, reused after its last MFMA read

    const int tid = threadIdx.x;
    const int e0g = blockIdx.x * ET;
    const int wave = tid >> 6, lane = tid & 63;
    const int lr = lane & 15, lg = lane >> 4;
    const int er = lane & 15, kg = lane >> 4;
    const int w = wave;
    const int ktl0 = w >> 1;          // owned kt within a 4-kt chunk
    const int hb = (w & 1) * 2;       // h-pair base

    // ---- geometry ----
    if (tid < ET) {
        const int e = e0g + tid;
        const int s = edge_index[e];
        const int d = edge_index[E_TOTAL + e];
        sidx[tid] = s; didx[tid] = d;
        const int g = graph_batch[s];
        const float* c = cell + g * 9;
        const float sx = edge_shift[e * 3], sy = edge_shift[e * 3 + 1], sz = edge_shift[e * 3 + 2];
        const float t0 = sx * c[0] + sy * c[3] + sz * c[6];
        const float t1 = sx * c[1] + sy * c[4] + sz * c[7];
        const float t2 = sx * c[2] + sy * c[5] + sz * c[8];
        const float r0 = pos[d * 3 + 0] - pos[s * 3 + 0] + t0;
        const float r1 = pos[d * 3 + 1] - pos[s * 3 + 1] + t1;
        const float r2 = pos[d * 3 + 2] - pos[s * 3 + 2] + t2;
        dist_s[tid] = sqrtf(r0 * r0 + r1 * r1 + r2 * r2);
    }
    __syncthreads();

    // ---- gather a-parts ----
    {
        const int e = tid >> 3, c = tid & 7;
        *(float4*)(xa1 + e * ASTR + c * 4) = *(const float4*)(nodes + (size_t)sidx[e] * NODE_D + c * 4);
        *(float4*)(xa2 + e * ASTR + c * 4) = *(const float4*)(nodes + (size_t)didx[e] * NODE_D + c * 4);
    }
    __syncthreads();

    const short8* WT8 = (const short8*)wsp;
    const int bcol = tid;
    const char* pA0 = (const char*)Pf + lane * 16;
    const char* pA1 = pA0 + 16384;

    f32x4 acc[4] = {{0.f,0.f,0.f,0.f},{0.f,0.f,0.f,0.f},{0.f,0.f,0.f,0.f},{0.f,0.f,0.f,0.f}};

    // hoist a2 for this thread's two h rows
    float2 a2v[2][4];
#pragma unroll
    for (int hh = 0; hh < 2; ++hh)
#pragma unroll
        for (int q = 0; q < 4; ++q)
            a2v[hh][q] = *(const float2*)(xa2 + ((hb + hh) * 16 + er) * ASTR + kg * 8 + q * 2);

#define BUILD_L0(buf, c)                                                          \
    {                                                                             \
        _Pragma("unroll")                                                         \
        for (int hh = 0; hh < 2; ++hh) {                                          \
            const int h = hb + hh;                                                \
            const float a1 = xa1[(h * 16 + er) * ASTR + (c) * 4 + ktl0];          \
            uint4 o;                                                              \
            o.x = f2b2(a1 * a2v[hh][0].x, a1 * a2v[hh][0].y);                     \
            o.y = f2b2(a1 * a2v[hh][1].x, a1 * a2v[hh][1].y);                     \
            o.z = f2b2(a1 * a2v[hh][2].x, a1 * a2v[hh][2].y);                     \
            o.w = f2b2(a1 * a2v[hh][3].x, a1 * a2v[hh][3].y);                     \
            *(uint4*)((buf) + ((ktl0 * 4 + h) * 64 + lane) * 8) = o;              \
        }                                                                         \
    }

#define MFMA4(pA, ktg)                                                            \
    {                                                                             \
        _Pragma("unroll")                                                         \
        for (int kt = 0; kt < 4; ++kt) {                                          \
            const short8 b = WT8[((ktg) + kt) * 512 + bcol];                      \
            _Pragma("unroll")                                                     \
            for (int h = 0; h < 4; ++h) {                                         \
                const short8 a = *(const short8*)((pA) + (kt * 4 + h) * 1024);    \
                acc[h] = __builtin_amdgcn_mfma_f32_16x16x32_bf16(a, b, acc[h], 0, 0, 0); \
            }                                                                     \
        }                                                                         \
    }

    // prologue: build chunk 0 into buf0
    BUILD_L0(Pf, 0);
    __syncthreads();

    // l0 pipeline: iterations 0..6 — mfma chunk c (buf c&1), build chunk c+1 (other buf)
#pragma unroll 1
    for (int c = 0; c < 7; ++c) {
        const char* pA = (c & 1) ? pA1 : pA0;
        MFMA4(pA, c * 4);
        ushort_t* nbuf = (c & 1) ? Pf : (Pf + 8192);
        BUILD_L0(nbuf, c + 1);
        if (c == 5) {
            // gather b-parts (no alias with xa) — overlapped with l0
            for (int i = tid; i < ET * 16; i += NTHR) {
                const int e = i >> 4, cc = i & 15;
                if (cc < 12) {
                    *(float4*)(b1s + e * BSTR + cc * 4) =
                        *(const float4*)(nodes + (size_t)sidx[e] * NODE_D + 32 + cc * 4);
                    *(float4*)(b2s + e * BSTR + cc * 4) =
                        *(const float4*)(nodes + (size_t)didx[e] * NODE_D + 32 + cc * 4);
                }
            }
        }
        __syncthreads();
    }

    // it7: mfma l0 chunk7 (buf1); build l1 cc=0 -> buf0
    MFMA4(pA1, 28);
    {
#pragma unroll
        for (int hh = 0; hh < 2; ++hh) {
            const int h = hb + hh;
            const int e = h * 16 + er;
            const int u1 = 2 * (0 * 4 + ktl0) + (kg >> 1);
            const float* b1p = b1s + e * BSTR + 3 * u1;
            const float ba = b1p[0], bbv = b1p[1], bcv = b1p[2];
            const float* b2p = b2s + e * BSTR + 3 * ((kg & 1) * 8);
            float pr[8];
#pragma unroll
            for (int jj = 0; jj < 8; ++jj)
                pr[jj] = ba * b2p[3 * jj] + bbv * b2p[3 * jj + 1] + bcv * b2p[3 * jj + 2];
            uint4 o;
            o.x = f2b2(pr[0], pr[1]); o.y = f2b2(pr[2], pr[3]);
            o.z = f2b2(pr[4], pr[5]); o.w = f2b2(pr[6], pr[7]);
            *(uint4*)(Pf + ((ktl0 * 4 + h) * 64 + lane) * 8) = o;
        }
    }
    __syncthreads();

    // it8: mfma l1 cc0 (buf0); build l1 cc=1 -> buf1 (LAST reader of b1s/b2s)
    MFMA4(pA0, 32);
    {
#pragma unroll
        for (int hh = 0; hh < 2; ++hh) {
            const int h = hb + hh;
            const int e = h * 16 + er;
            const int u1 = 2 * (1 * 4 + ktl0) + (kg >> 1);
            const float* b1p = b1s + e * BSTR + 3 * u1;
            const float ba = b1p[0], bbv = b1p[1], bcv = b1p[2];
            const float* b2p = b2s + e * BSTR + 3 * ((kg & 1) * 8);
            float pr[8];
#pragma unroll
            for (int jj = 0; jj < 8; ++jj)
                pr[jj] = ba * b2p[3 * jj] + bbv * b2p[3 * jj + 1] + bcv * b2p[3 * jj + 2];
            uint4 o;
            o.x = f2b2(pr[0], pr[1]); o.y = f2b2(pr[2], pr[3]);
            o.z = f2b2(pr[4], pr[5]); o.w = f2b2(pr[6], pr[7]);
            *(uint4*)(Pf + 8192 + ((ktl0 * 4 + h) * 64 + lane) * 8) = o;
        }
    }
    __syncthreads();

    // it9: mfma l1 cc1 (buf1); c-gather (xa AND b both dead after it8 barrier)
    MFMA4(pA1, 36);
    for (int i = tid; i < ET * 16; i += NTHR) {
        const int e = i >> 4, cc = i & 15;
        if (cc < 10) {
            *(float4*)(c1s + e * CSTR + cc * 4) =
                *(const float4*)(nodes + (size_t)sidx[e] * NODE_D + 80 + cc * 4);
            *(float4*)(c2s + e * CSTR + cc * 4) =
                *(const float4*)(nodes + (size_t)didx[e] * NODE_D + 80 + cc * 4);
        }
    }
    __syncthreads();

    // it10 (build-only): l2 build -> buf0; demb build -> buf1 (dembF)
    {
        const int ktl = w >> 2, h2 = w & 3;
        const int u2 = ktl * 4 + kg;
        const int e = h2 * 16 + er;
        const float* c1p = c1s + e * CSTR + 5 * u2;
        const float ca = c1p[0], cb = c1p[1], cc2 = c1p[2], cd = c1p[3], ce = c1p[4];
        float pr[8];
#pragma unroll
        for (int jj = 0; jj < 8; ++jj) {
            const float* c2p = c2s + e * CSTR + 5 * jj;
            pr[jj] = ca * c2p[0] + cb * c2p[1] + cc2 * c2p[2] + cd * c2p[3] + ce * c2p[4];
        }
        uint4 o;
        o.x = f2b2(pr[0], pr[1]); o.y = f2b2(pr[2], pr[3]);
        o.z = f2b2(pr[4], pr[5]); o.w = f2b2(pr[6], pr[7]);
        *(uint4*)(Pf + ((ktl * 4 + h2) * 64 + lane) * 8) = o;
    }
    for (int i = tid; i < ET * 64; i += NTHR) {
        const int e = i >> 6, k = i & 63;
        const float d = dist_s[e];
        const float t = d - (7.0f / 63.0f) * (float)k;
        const float rbf = __expf(-40.5f * t * t);
        const float env = (d < 7.0f) ? (0.5f * (__cosf(d * (3.14159265358979f / 7.0f)) + 1.0f)) : 0.0f;
        const int ktl = k >> 5, kgd = (k >> 3) & 3, jj = k & 7, half = e >> 4, row = e & 15;
        dembF[((ktl * 4 + half) * 64 + kgd * 16 + row) * 8 + jj] = f2b(rbf * env);
    }
    __syncthreads();

    // it11: mfma l2 (buf0, 2 kt); then filter GEMM1 (reads dembF, written it10)
#pragma unroll
    for (int kt = 0; kt < 2; ++kt) {
        const short8 b = WT8[(40 + kt) * 512 + bcol];
#pragma unroll
        for (int h = 0; h < 4; ++h) {
            const short8 a = *(const short8*)(pA0 + (kt * 4 + h) * 1024);
            acc[h] = __builtin_amdgcn_mfma_f32_16x16x32_bf16(a, b, acc[h], 0, 0, 0);
        }
    }

    // ---- filter GEMM1: h1 = silu(demb @ df_w1 + b1) -> h1F (c region dead) ----
    {
        f32x4 f[4] = {{0.f,0.f,0.f,0.f},{0.f,0.f,0.f,0.f},{0.f,0.f,0.f,0.f},{0.f,0.f,0.f,0.f}};
        const char* dA = (const char*)dembF + lane * 16;
#pragma unroll
        for (int kt = 0; kt < 2; ++kt) {
            const short8 b = WT8[WS_WF1 / 8 + kt * 512 + bcol];
#pragma unroll
            for (int h = 0; h < 4; ++h) {
                const short8 a = *(const short8*)(dA + (kt * 4 + h) * 1024);
                f[h] = __builtin_amdgcn_mfma_f32_16x16x32_bf16(a, b, f[h], 0, 0, 0);
            }
        }
        __syncthreads();   // h1F aliases c1s region — drain c reads before write
        const int n = wave * 16 + lr;
        const float bb = df_b1[n];
        const int ktl = n >> 5, kg2 = (n >> 3) & 3, jjn = n & 7;
#pragma unroll
        for (int h = 0; h < 4; ++h)
#pragma unroll
            for (int r = 0; r < 4; ++r)
                h1F[((ktl * 4 + h) * 64 + kg2 * 16 + lg * 4 + r) * 8 + jjn] = f2b(silu_f(f[h][r] + bb));
    }
    __syncthreads();

    // ---- filter GEMM2 -> dfilter regs + LN partials ----
    f32x4 d[4] = {{0.f,0.f,0.f,0.f},{0.f,0.f,0.f,0.f},{0.f,0.f,0.f,0.f},{0.f,0.f,0.f,0.f}};
    {
        const char* hA = (const char*)h1F + lane * 16;
#pragma unroll
        for (int kt = 0; kt < 4; ++kt) {
            const short8 b = WT8[WS_WF2 / 8 + kt * 512 + bcol];
#pragma unroll
            for (int h = 0; h < 4; ++h) {
                const short8 a = *(const short8*)(hA + (kt * 4 + h) * 1024);
                d[h] = __builtin_amdgcn_mfma_f32_16x16x32_bf16(a, b, d[h], 0, 0, 0);
            }
        }
        const int n = wave * 16 + lr;
        const float b2v = df_b2[n];
#pragma unroll
        for (int h = 0; h < 4; ++h)
#pragma unroll
            for (int r = 0; r < 4; ++r) d[h][r] += b2v;
    }
#pragma unroll
    for (int h = 0; h < 4; ++h) {
#pragma unroll
        for (int r = 0; r < 4; ++r) {
            const float v = acc[h][r];
            float s1 = v, s2 = v * v;
            s1 += __shfl_xor(s1, 1);  s2 += __shfl_xor(s2, 1);
            s1 += __shfl_xor(s1, 2);  s2 += __shfl_xor(s2, 2);
            s1 += __shfl_xor(s1, 4);  s2 += __shfl_xor(s2, 4);
            s1 += __shfl_xor(s1, 8);  s2 += __shfl_xor(s2, 8);
            if (lr == 0) {
                const int idx = ((wave * 4 + h) * 4 + lg) * 4 + r;
                red1[idx] = s1;
                red1[512 + idx] = s2;
            }
        }
    }
    __syncthreads();
    if (tid < ET) {
        const int h = tid >> 4, g = (tid >> 2) & 3, r = tid & 3;
        float s1 = 0.f, s2 = 0.f;
#pragma unroll
        for (int ww = 0; ww < 8; ++ww) {
            const int idx = ((ww * 4 + h) * 4 + g) * 4 + r;
            s1 += red1[idx];
            s2 += red1[512 + idx];
        }
        const float mu = s1 * (1.0f / 128.0f);
        const float var = s2 * (1.0f / 128.0f) - mu * mu;
        mu_s[tid] = mu;
        rstd_s[tid] = rsqrtf(var + 1e-5f);
    }
    __syncthreads();

    // ---- regulated -> regF (fragment-linear bf16) ----
    {
        const int n = wave * 16 + lr;
        const float gv = ln_g[n], bv = ln_b[n];
        const int ktl = n >> 5, kg2 = (n >> 3) & 3, jjn = n & 7;
#pragma unroll
        for (int h = 0; h < 4; ++h) {
#pragma unroll
            for (int r = 0; r < 4; ++r) {
                const int row = lg * 4 + r, e = h * 16 + row;
                const float ln = (acc[h][r] - mu_s[e]) * rstd_s[e] * gv + bv;
                regF[((ktl * 4 + h) * 64 + kg2 * 16 + row) * 8 + jjn] = f2b(ln * d[h][r]);
            }
        }
    }
    __syncthreads();

    // ---- MLP: out = silu(reg @ w1 + b1) @ w2 + b2  (two q-passes) ----
    {
        float po[4][4];
#pragma unroll
        for (int h = 0; h < 4; ++h)
#pragma unroll
            for (int r = 0; r < 4; ++r) po[h][r] = 0.f;
        const char* rA = (const char*)regF + lane * 16;
#pragma unroll 1
        for (int qp = 0; qp < 2; ++qp) {
            f32x4 m[2][4];
#pragma unroll
            for (int qq = 0; qq < 2; ++qq)
#pragma unroll
                for (int h = 0; h < 4; ++h) m[qq][h] = (f32x4){0.f,0.f,0.f,0.f};
#pragma unroll
            for (int kt = 0; kt < 4; ++kt) {
                short8 a[4];
#pragma unroll
                for (int h = 0; h < 4; ++h)
                    a[h] = *(const short8*)(rA + (kt * 4 + h) * 1024);
                const int base = WS_WM1 / 8 + kt * 2048 + wave * 256 + lane + qp * 128;
#pragma unroll
                for (int qq = 0; qq < 2; ++qq) {
                    const short8 b = WT8[base + qq * 64];
#pragma unroll
                    for (int h = 0; h < 4; ++h)
                        m[qq][h] = __builtin_amdgcn_mfma_f32_16x16x32_bf16(a[h], b, m[qq][h], 0, 0, 0);
                }
            }
#pragma unroll
            for (int qq = 0; qq < 2; ++qq) {
                const int n = (wave * 4 + qp * 2 + qq) * 16 + lr;
                const float b1v = mlp_b1[n];
                const float w2v = mlp_w2[n];
#pragma unroll
                for (int h = 0; h < 4; ++h)
#pragma unroll
                    for (int r = 0; r < 4; ++r)
                        po[h][r] += silu_f(m[qq][h][r] + b1v) * w2v;
            }
        }
#pragma unroll
        for (int h = 0; h < 4; ++h) {
#pragma unroll
            for (int r = 0; r < 4; ++r) {
                float a = po[h][r];
                a += __shfl_xor(a, 1);
                a += __shfl_xor(a, 2);
                a += __shfl_xor(a, 4);
                a += __shfl_xor(a, 8);
                if (lr == 0) red2[((wave * 4 + h) * 4 + lg) * 4 + r] = a;
            }
        }
    }
    __syncthreads();
    if (tid < ET) {
        const int h = tid >> 4, g = (tid >> 2) & 3, r = tid & 3;
        float s = 0.f;
#pragma unroll
        for (int ww = 0; ww < 8; ++ww)
            s += red2[((ww * 4 + h) * 4 + g) * 4 + r];
        out[e0g + tid] = s + mlp_b2[0];
    }
}

extern "C" void kernel_launch(void* const* d_in, const int* in_sizes, int n_in,
                              void* d_out, int out_size, void* d_ws, size_t ws_size,
                              hipStream_t stream) {
    const float* nodes      = (const float*)d_in[0];
    const int*   edge_index = (const int*)  d_in[1];
    const int*   graph_b    = (const int*)  d_in[2];
    const float* cell       = (const float*)d_in[3];
    const float* edge_shift = (const float*)d_in[4];
    const float* pos        = (const float*)d_in[5];
    const float* W0         = (const float*)d_in[6];
    const float* W1         = (const float*)d_in[7];
    const float* W2         = (const float*)d_in[8];
    const float* ln_g       = (const float*)d_in[9];
    const float* ln_b       = (const float*)d_in[10];
    const float* df_w1      = (const float*)d_in[11];
    const float* df_b1      = (const float*)d_in[12];
    const float* df_w2      = (const float*)d_in[13];
    const float* df_b2      = (const float*)d_in[14];
    const float* mlp_w1     = (const float*)d_in[15];
    const float* mlp_b1     = (const float*)d_in[16];
    const float* mlp_w2     = (const float*)d_in[17];
    const float* mlp_b2     = (const float*)d_in[18];
    float* out = (float*)d_out;
    ushort_t* ws = (ushort_t*)d_ws;

    hipLaunchKernelGGL(prep_weights, dim3((WS_TOTAL + 255) / 256), dim3(256), 0, stream,
                       W0, W1, W2, df_w1, df_w2, mlp_w1, ws);

    const int E = in_sizes[1] / 2;
    const int grid = E / ET;   // 6250
    hipLaunchKernelGGL(fused_edge_kernel, dim3(grid), dim3(NTHR), 0, stream,
                       nodes, edge_index, graph_b, cell, edge_shift, pos,
                       ln_g, ln_b, df_b1, df_b2, mlp_b1, mlp_w2, mlp_b2,
                       ws, out);
}

// Round 12
// 512.127 us; speedup vs baseline: 1.4817x; 1.1109x over previous
//
#include <hip/hip_runtime.h>
#include <hip/hip_bf16.h>
#include <math.h>

typedef unsigned short ushort_t;
typedef short short8 __attribute__((ext_vector_type(8)));
typedef float f32x4 __attribute__((ext_vector_type(4)));

#define E_TOTAL 400000
#define ET 64          // edges per block
#define NTHR 512       // 8 waves
#define NODE_D 120
#define ASTR 36        // a-part stride (er*4 mod 32 banks -> 2-way, free)
#define BSTR 52        // b-part stride (er*20 mod 32 -> 8 banks, 2-way) was 48 = 8-way
#define CSTR 44        // c-part stride (er*12 mod 32 -> 8 banks, 2-way)

#define ALPHA 0.0272772362793f   // 1/sqrt(1344)
#define S_L1  0.57735026918962f  // 1/sqrt(3)
#define S_L2  0.44721359549996f  // 1/sqrt(5)

#define WS_WF1 172032
#define WS_WF2 180224
#define WS_WM1 196608
#define WS_TOTAL 262144

__device__ __forceinline__ ushort_t f2b(float f) {
    unsigned int b = __float_as_uint(f);
    b += 0x7FFFu + ((b >> 16) & 1u);   // RNE
    return (ushort_t)(b >> 16);
}
__device__ __forceinline__ unsigned int f2b2(float a, float b) {
    __hip_bfloat162 h = __float22bfloat162_rn(make_float2(a, b));  // v_cvt_pk_bf16_f32
    union { __hip_bfloat162 h2; unsigned int u; } cv; cv.h2 = h;
    return cv.u;
}
__device__ __forceinline__ float silu_f(float x) { return x / (1.0f + __expf(-x)); }

__global__ __launch_bounds__(256) void prep_weights(
    const float* __restrict__ W0, const float* __restrict__ W1, const float* __restrict__ W2,
    const float* __restrict__ df_w1, const float* __restrict__ df_w2,
    const float* __restrict__ mlp_w1, ushort_t* __restrict__ ws)
{
    const int i = blockIdx.x * 256 + threadIdx.x;
    if (i >= WS_TOTAL) return;
    float v;
    if (i < WS_WF1) {            // TP: 42 kt x 8 nt
        const int r = i;
        const int kt = r >> 12, nt = (r >> 9) & 7, l = (r >> 3) & 63, jj = r & 7;
        const int k = kt * 32 + ((l >> 4) << 3) + jj;
        const int n = nt * 16 + (l & 15);
        if (k < 1024)      v = W0[k * 128 + n] * ALPHA;
        else if (k < 1280) v = W1[(k - 1024) * 128 + n] * (ALPHA * S_L1);
        else               v = W2[(k - 1280) * 128 + n] * (ALPHA * S_L2);
    } else if (i < WS_WF2) {     // df_w1
        const int r = i - WS_WF1;
        const int kt = r >> 12, nt = (r >> 9) & 7, l = (r >> 3) & 63, jj = r & 7;
        v = df_w1[(kt * 32 + ((l >> 4) << 3) + jj) * 128 + nt * 16 + (l & 15)];
    } else if (i < WS_WM1) {     // df_w2
        const int r = i - WS_WF2;
        const int kt = r >> 12, nt = (r >> 9) & 7, l = (r >> 3) & 63, jj = r & 7;
        v = df_w2[(kt * 32 + ((l >> 4) << 3) + jj) * 128 + nt * 16 + (l & 15)];
    } else {                     // mlp_w1
        const int r = i - WS_WM1;
        const int kt = r >> 14, nt = (r >> 9) & 31, l = (r >> 3) & 63, jj = r & 7;
        v = mlp_w1[(kt * 32 + ((l >> 4) << 3) + jj) * 512 + nt * 16 + (l & 15)];
    }
    ws[i] = f2b(v);
}

__global__ __launch_bounds__(NTHR, 4) void fused_edge_kernel(
    const float* __restrict__ nodes, const int* __restrict__ edge_index,
    const int* __restrict__ graph_batch, const float* __restrict__ cell,
    const float* __restrict__ edge_shift, const float* __restrict__ pos,
    const float* __restrict__ ln_g, const float* __restrict__ ln_b,
    const float* __restrict__ df_b1, const float* __restrict__ df_b2,
    const float* __restrict__ mlp_b1, const float* __restrict__ mlp_w2,
    const float* __restrict__ mlp_b2,
    const ushort_t* __restrict__ wsp, float* __restrict__ out)
{
    // Pf: two 16 KB A-fragment buffers (4 kt x 4 h x 64 lanes x 8 us each).
    __shared__ __align__(16) ushort_t Pf[16384];
    // Xb arena (45056 B):
    //  xa1 [0,9216) xa2 [9216,18432)          (l0 operands)
    //  b1s [18432,31744) b2s [31744,45056)    (l1; NO alias with xa; BSTR=52)
    //  c1s [0,11264) c2s [11264,22528)        (l2; aliases xa + b1s head ->
    //                                          c-gather only after last b read)
    //  post-TP: h1F [0,16384) regF [16384,32768) red1 [32768,36864) red2 [36864,38912)
    __shared__ __align__(16) char Xb[45056];
    __shared__ float dist_s[ET];
    __shared__ int sidx[ET], didx[ET];
    __shared__ float mu_s[ET], rstd_s[ET];

    float* xa1 = (float*)Xb;
    float* xa2 = (float*)(Xb + 9216);
    float* b1s = (float*)(Xb + 18432);
    float* b2s = (float*)(Xb + 31744);
    float* c1s = (float*)Xb;
    float* c2s = (float*)(Xb + 11264);
    ushort_t* h1F  = (ushort_t*)Xb;
    ushort_t* regF = (ushort_t*)(Xb + 16384);
    float* red1 = (float*)(Xb + 32768);
    float* red2 = (float*)(Xb + 36864);
    ushort_t* dembF = Pf + 8192;   // buf1 region, reused after its last MFMA read

    const int tid = threadIdx.x;
    const int e0g = blockIdx.x * ET;
    const int wave = tid >> 6, lane = tid & 63;
    const int lr = lane & 15, lg = lane >> 4;
    const int er = lane & 15, kg = lane >> 4;
    const int w = wave;
    const int ktl0 = w >> 1;          // owned kt within a 4-kt chunk
    const int hb = (w & 1) * 2;       // h-pair base

    // ---- geometry ----
    if (tid < ET) {
        const int e = e0g + tid;
        const int s = edge_index[e];
        const int d = edge_index[E_TOTAL + e];
        sidx[tid] = s; didx[tid] = d;
        const int g = graph_batch[s];
        const float* c = cell + g * 9;
        const float sx = edge_shift[e * 3], sy = edge_shift[e * 3 + 1], sz = edge_shift[e * 3 + 2];
        const float t0 = sx * c[0] + sy * c[3] + sz * c[6];
        const float t1 = sx * c[1] + sy * c[4] + sz * c[7];
        const float t2 = sx * c[2] + sy * c[5] + sz * c[8];
        const float r0 = pos[d * 3 + 0] - pos[s * 3 + 0] + t0;
        const float r1 = pos[d * 3 + 1] - pos[s * 3 + 1] + t1;
        const float r2 = pos[d * 3 + 2] - pos[s * 3 + 2] + t2;
        dist_s[tid] = sqrtf(r0 * r0 + r1 * r1 + r2 * r2);
    }
    __syncthreads();

    // ---- gather a-parts ----
    {
        const int e = tid >> 3, c = tid & 7;
        *(float4*)(xa1 + e * ASTR + c * 4) = *(const float4*)(nodes + (size_t)sidx[e] * NODE_D + c * 4);
        *(float4*)(xa2 + e * ASTR + c * 4) = *(const float4*)(nodes + (size_t)didx[e] * NODE_D + c * 4);
    }
    __syncthreads();

    const short8* WT8 = (const short8*)wsp;
    const int bcol = tid;
    const char* pA0 = (const char*)Pf + lane * 16;
    const char* pA1 = pA0 + 16384;
    ushort_t* buf0 = Pf;
    ushort_t* buf1 = Pf + 8192;

    f32x4 acc[4] = {{0.f,0.f,0.f,0.f},{0.f,0.f,0.f,0.f},{0.f,0.f,0.f,0.f},{0.f,0.f,0.f,0.f}};

    // hoist a2 for this thread's two h rows
    float2 a2v[2][4];
#pragma unroll
    for (int hh = 0; hh < 2; ++hh)
#pragma unroll
        for (int q = 0; q < 4; ++q)
            a2v[hh][q] = *(const float2*)(xa2 + ((hb + hh) * 16 + er) * ASTR + kg * 8 + q * 2);

#define BUILD_L0(buf, c)                                                          \
    {                                                                             \
        _Pragma("unroll")                                                         \
        for (int hh = 0; hh < 2; ++hh) {                                          \
            const int h = hb + hh;                                                \
            const float a1 = xa1[(h * 16 + er) * ASTR + (c) * 4 + ktl0];          \
            uint4 o;                                                              \
            o.x = f2b2(a1 * a2v[hh][0].x, a1 * a2v[hh][0].y);                     \
            o.y = f2b2(a1 * a2v[hh][1].x, a1 * a2v[hh][1].y);                     \
            o.z = f2b2(a1 * a2v[hh][2].x, a1 * a2v[hh][2].y);                     \
            o.w = f2b2(a1 * a2v[hh][3].x, a1 * a2v[hh][3].y);                     \
            *(uint4*)((buf) + ((ktl0 * 4 + h) * 64 + lane) * 8) = o;              \
        }                                                                         \
    }

#define BUILD_L1(buf, cc)                                                         \
    {                                                                             \
        _Pragma("unroll")                                                         \
        for (int hh = 0; hh < 2; ++hh) {                                          \
            const int h = hb + hh;                                                \
            const int e = h * 16 + er;                                            \
            const int u1 = 2 * ((cc) * 4 + ktl0) + (kg >> 1);                     \
            const float* b1p = b1s + e * BSTR + 3 * u1;                           \
            const float ba = b1p[0], bbv = b1p[1], bcv = b1p[2];                  \
            const float* b2p = b2s + e * BSTR + 3 * ((kg & 1) * 8);               \
            float pr[8];                                                          \
            _Pragma("unroll")                                                     \
            for (int jj = 0; jj < 8; ++jj)                                        \
                pr[jj] = ba * b2p[3 * jj] + bbv * b2p[3 * jj + 1]                 \
                       + bcv * b2p[3 * jj + 2];                                   \
            uint4 o;                                                              \
            o.x = f2b2(pr[0], pr[1]); o.y = f2b2(pr[2], pr[3]);                   \
            o.z = f2b2(pr[4], pr[5]); o.w = f2b2(pr[6], pr[7]);                   \
            *(uint4*)((buf) + ((ktl0 * 4 + h) * 64 + lane) * 8) = o;              \
        }                                                                         \
    }

#define MFMA4(pA, ktg)                                                            \
    {                                                                             \
        _Pragma("unroll")                                                         \
        for (int kt = 0; kt < 4; ++kt) {                                          \
            const short8 b = WT8[((ktg) + kt) * 512 + bcol];                      \
            _Pragma("unroll")                                                     \
            for (int h = 0; h < 4; ++h) {                                         \
                const short8 a = *(const short8*)((pA) + (kt * 4 + h) * 1024);    \
                acc[h] = __builtin_amdgcn_mfma_f32_16x16x32_bf16(a, b, acc[h], 0, 0, 0); \
            }                                                                     \
        }                                                                         \
    }

    // ---- l0 pipeline, hand-unrolled (no dynamic buffer selects) ----
    BUILD_L0(buf0, 0);
    __syncthreads();
    MFMA4(pA0, 0);  BUILD_L0(buf1, 1);  __syncthreads();
    MFMA4(pA1, 4);  BUILD_L0(buf0, 2);  __syncthreads();
    MFMA4(pA0, 8);  BUILD_L0(buf1, 3);  __syncthreads();
    MFMA4(pA1, 12); BUILD_L0(buf0, 4);  __syncthreads();
    MFMA4(pA0, 16); BUILD_L0(buf1, 5);  __syncthreads();
    MFMA4(pA1, 20); BUILD_L0(buf0, 6);
    // b-gather (no alias with xa) — overlapped with l0 tail
    for (int i = tid; i < ET * 16; i += NTHR) {
        const int e = i >> 4, cc = i & 15;
        if (cc < 12) {
            *(float4*)(b1s + e * BSTR + cc * 4) =
                *(const float4*)(nodes + (size_t)sidx[e] * NODE_D + 32 + cc * 4);
            *(float4*)(b2s + e * BSTR + cc * 4) =
                *(const float4*)(nodes + (size_t)didx[e] * NODE_D + 32 + cc * 4);
        }
    }
    __syncthreads();
    MFMA4(pA0, 24); BUILD_L0(buf1, 7);  __syncthreads();
    MFMA4(pA1, 28); BUILD_L1(buf0, 0);  __syncthreads();
    MFMA4(pA0, 32); BUILD_L1(buf1, 1);  __syncthreads();   // LAST reader of b1s/b2s
    MFMA4(pA1, 36);
    // c-gather (xa and b both dead after previous barrier)
    for (int i = tid; i < ET * 16; i += NTHR) {
        const int e = i >> 4, cc = i & 15;
        if (cc < 10) {
            *(float4*)(c1s + e * CSTR + cc * 4) =
                *(const float4*)(nodes + (size_t)sidx[e] * NODE_D + 80 + cc * 4);
            *(float4*)(c2s + e * CSTR + cc * 4) =
                *(const float4*)(nodes + (size_t)didx[e] * NODE_D + 80 + cc * 4);
        }
    }
    __syncthreads();

    // build-only stage: l2 -> buf0; demb -> buf1 (dembF)
    {
        const int ktl = w >> 2, h2 = w & 3;
        const int u2 = ktl * 4 + kg;
        const int e = h2 * 16 + er;
        const float* c1p = c1s + e * CSTR + 5 * u2;
        const float ca = c1p[0], cb = c1p[1], cc2 = c1p[2], cd = c1p[3], ce = c1p[4];
        float pr[8];
#pragma unroll
        for (int jj = 0; jj < 8; ++jj) {
            const float* c2p = c2s + e * CSTR + 5 * jj;
            pr[jj] = ca * c2p[0] + cb * c2p[1] + cc2 * c2p[2] + cd * c2p[3] + ce * c2p[4];
        }
        uint4 o;
        o.x = f2b2(pr[0], pr[1]); o.y = f2b2(pr[2], pr[3]);
        o.z = f2b2(pr[4], pr[5]); o.w = f2b2(pr[6], pr[7]);
        *(uint4*)(buf0 + ((ktl * 4 + h2) * 64 + lane) * 8) = o;
    }
    for (int i = tid; i < ET * 64; i += NTHR) {
        const int e = i >> 6, k = i & 63;
        const float d = dist_s[e];
        const float t = d - (7.0f / 63.0f) * (float)k;
        const float rbf = __expf(-40.5f * t * t);
        const float env = (d < 7.0f) ? (0.5f * (__cosf(d * (3.14159265358979f / 7.0f)) + 1.0f)) : 0.0f;
        const int ktl = k >> 5, kgd = (k >> 3) & 3, jj = k & 7, half = e >> 4, row = e & 15;
        dembF[((ktl * 4 + half) * 64 + kgd * 16 + row) * 8 + jj] = f2b(rbf * env);
    }
    __syncthreads();

    // mfma l2 (buf0, 2 kt)
#pragma unroll
    for (int kt = 0; kt < 2; ++kt) {
        const short8 b = WT8[(40 + kt) * 512 + bcol];
#pragma unroll
        for (int h = 0; h < 4; ++h) {
            const short8 a = *(const short8*)(pA0 + (kt * 4 + h) * 1024);
            acc[h] = __builtin_amdgcn_mfma_f32_16x16x32_bf16(a, b, acc[h], 0, 0, 0);
        }
    }

    // ---- filter GEMM1: h1 = silu(demb @ df_w1 + b1) -> h1F (c region dead) ----
    {
        f32x4 f[4] = {{0.f,0.f,0.f,0.f},{0.f,0.f,0.f,0.f},{0.f,0.f,0.f,0.f},{0.f,0.f,0.f,0.f}};
        const char* dA = (const char*)dembF + lane * 16;
#pragma unroll
        for (int kt = 0; kt < 2; ++kt) {
            const short8 b = WT8[WS_WF1 / 8 + kt * 512 + bcol];
#pragma unroll
            for (int h = 0; h < 4; ++h) {
                const short8 a = *(const short8*)(dA + (kt * 4 + h) * 1024);
                f[h] = __builtin_amdgcn_mfma_f32_16x16x32_bf16(a, b, f[h], 0, 0, 0);
            }
        }
        __syncthreads();   // h1F aliases c1s region — drain c reads before write
        const int n = wave * 16 + lr;
        const float bb = df_b1[n];
        const int ktl = n >> 5, kg2 = (n >> 3) & 3, jjn = n & 7;
#pragma unroll
        for (int h = 0; h < 4; ++h)
#pragma unroll
            for (int r = 0; r < 4; ++r)
                h1F[((ktl * 4 + h) * 64 + kg2 * 16 + lg * 4 + r) * 8 + jjn] = f2b(silu_f(f[h][r] + bb));
    }
    __syncthreads();

    // ---- filter GEMM2 -> dfilter regs + LN partials ----
    f32x4 d[4] = {{0.f,0.f,0.f,0.f},{0.f,0.f,0.f,0.f},{0.f,0.f,0.f,0.f},{0.f,0.f,0.f,0.f}};
    {
        const char* hA = (const char*)h1F + lane * 16;
#pragma unroll
        for (int kt = 0; kt < 4; ++kt) {
            const short8 b = WT8[WS_WF2 / 8 + kt * 512 + bcol];
#pragma unroll
            for (int h = 0; h < 4; ++h) {
                const short8 a = *(const short8*)(hA + (kt * 4 + h) * 1024);
                d[h] = __builtin_amdgcn_mfma_f32_16x16x32_bf16(a, b, d[h], 0, 0, 0);
            }
        }
        const int n = wave * 16 + lr;
        const float b2v = df_b2[n];
#pragma unroll
        for (int h = 0; h < 4; ++h)
#pragma unroll
            for (int r = 0; r < 4; ++r) d[h][r] += b2v;
    }
#pragma unroll
    for (int h = 0; h < 4; ++h) {
#pragma unroll
        for (int r = 0; r < 4; ++r) {
            const float v = acc[h][r];
            float s1 = v, s2 = v * v;
            s1 += __shfl_xor(s1, 1);  s2 += __shfl_xor(s2, 1);
            s1 += __shfl_xor(s1, 2);  s2 += __shfl_xor(s2, 2);
            s1 += __shfl_xor(s1, 4);  s2 += __shfl_xor(s2, 4);
            s1 += __shfl_xor(s1, 8);  s2 += __shfl_xor(s2, 8);
            if (lr == 0) {
                const int idx = ((wave * 4 + h) * 4 + lg) * 4 + r;
                red1[idx] = s1;
                red1[512 + idx] = s2;
            }
        }
    }
    __syncthreads();
    if (tid < ET) {
        const int h = tid >> 4, g = (tid >> 2) & 3, r = tid & 3;
        float s1 = 0.f, s2 = 0.f;
#pragma unroll
        for (int ww = 0; ww < 8; ++ww) {
            const int idx = ((ww * 4 + h) * 4 + g) * 4 + r;
            s1 += red1[idx];
            s2 += red1[512 + idx];
        }
        const float mu = s1 * (1.0f / 128.0f);
        const float var = s2 * (1.0f / 128.0f) - mu * mu;
        mu_s[tid] = mu;
        rstd_s[tid] = rsqrtf(var + 1e-5f);
    }
    __syncthreads();

    // ---- regulated -> regF (fragment-linear bf16) ----
    {
        const int n = wave * 16 + lr;
        const float gv = ln_g[n], bv = ln_b[n];
        const int ktl = n >> 5, kg2 = (n >> 3) & 3, jjn = n & 7;
#pragma unroll
        for (int h = 0; h < 4; ++h) {
#pragma unroll
            for (int r = 0; r < 4; ++r) {
                const int row = lg * 4 + r, e = h * 16 + row;
                const float ln = (acc[h][r] - mu_s[e]) * rstd_s[e] * gv + bv;
                regF[((ktl * 4 + h) * 64 + kg2 * 16 + row) * 8 + jjn] = f2b(ln * d[h][r]);
            }
        }
    }
    __syncthreads();

    // ---- MLP: out = silu(reg @ w1 + b1) @ w2 + b2  (two q-passes) ----
    {
        float po[4][4];
#pragma unroll
        for (int h = 0; h < 4; ++h)
#pragma unroll
            for (int r = 0; r < 4; ++r) po[h][r] = 0.f;
        const char* rA = (const char*)regF + lane * 16;
#pragma unroll 1
        for (int qp = 0; qp < 2; ++qp) {
            f32x4 m[2][4];
#pragma unroll
            for (int qq = 0; qq < 2; ++qq)
#pragma unroll
                for (int h = 0; h < 4; ++h) m[qq][h] = (f32x4){0.f,0.f,0.f,0.f};
#pragma unroll
            for (int kt = 0; kt < 4; ++kt) {
                short8 a[4];
#pragma unroll
                for (int h = 0; h < 4; ++h)
                    a[h] = *(const short8*)(rA + (kt * 4 + h) * 1024);
                const int base = WS_WM1 / 8 + kt * 2048 + wave * 256 + lane + qp * 128;
#pragma unroll
                for (int qq = 0; qq < 2; ++qq) {
                    const short8 b = WT8[base + qq * 64];
#pragma unroll
                    for (int h = 0; h < 4; ++h)
                        m[qq][h] = __builtin_amdgcn_mfma_f32_16x16x32_bf16(a[h], b, m[qq][h], 0, 0, 0);
                }
            }
#pragma unroll
            for (int qq = 0; qq < 2; ++qq) {
                const int n = (wave * 4 + qp * 2 + qq) * 16 + lr;
                const float b1v = mlp_b1[n];
                const float w2v = mlp_w2[n];
#pragma unroll
                for (int h = 0; h < 4; ++h)
#pragma unroll
                    for (int r = 0; r < 4; ++r)
                        po[h][r] += silu_f(m[qq][h][r] + b1v) * w2v;
            }
        }
#pragma unroll
        for (int h = 0; h < 4; ++h) {
#pragma unroll
            for (int r = 0; r < 4; ++r) {
                float a = po[h][r];
                a += __shfl_xor(a, 1);
                a += __shfl_xor(a, 2);
                a += __shfl_xor(a, 4);
                a += __shfl_xor(a, 8);
                if (lr == 0) red2[((wave * 4 + h) * 4 + lg) * 4 + r] = a;
            }
        }
    }
    __syncthreads();
    if (tid < ET) {
        const int h = tid >> 4, g = (tid >> 2) & 3, r = tid & 3;
        float s = 0.f;
#pragma unroll
        for (int ww = 0; ww < 8; ++ww)
            s += red2[((ww * 4 + h) * 4 + g) * 4 + r];
        out[e0g + tid] = s + mlp_b2[0];
    }
}

extern "C" void kernel_launch(void* const* d_in, const int* in_sizes, int n_in,
                              void* d_out, int out_size, void* d_ws, size_t ws_size,
                              hipStream_t stream) {
    const float* nodes      = (const float*)d_in[0];
    const int*   edge_index = (const int*)  d_in[1];
    const int*   graph_b    = (const int*)  d_in[2];
    const float* cell       = (const float*)d_in[3];
    const float* edge_shift = (const float*)d_in[4];
    const float* pos        = (const float*)d_in[5];
    const float* W0         = (const float*)d_in[6];
    const float* W1         = (const float*)d_in[7];
    const float* W2         = (const float*)d_in[8];
    const float* ln_g       = (const float*)d_in[9];
    const float* ln_b       = (const float*)d_in[10];
    const float* df_w1      = (const float*)d_in[11];
    const float* df_b1      = (const float*)d_in[12];
    const float* df_w2      = (const float*)d_in[13];
    const float* df_b2      = (const float*)d_in[14];
    const float* mlp_w1     = (const float*)d_in[15];
    const float* mlp_b1     = (const float*)d_in[16];
    const float* mlp_w2     = (const float*)d_in[17];
    const float* mlp_b2     = (const float*)d_in[18];
    float* out = (float*)d_out;
    ushort_t* ws = (ushort_t*)d_ws;

    hipLaunchKernelGGL(prep_weights, dim3((WS_TOTAL + 255) / 256), dim3(256), 0, stream,
                       W0, W1, W2, df_w1, df_w2, mlp_w1, ws);

    const int E = in_sizes[1] / 2;
    const int grid = E / ET;   // 6250
    hipLaunchKernelGGL(fused_edge_kernel, dim3(grid), dim3(NTHR), 0, stream,
                       nodes, edge_index, graph_b, cell, edge_shift, pos,
                       ln_g, ln_b, df_b1, df_b2, mlp_b1, mlp_w2, mlp_b2,
                       ws, out);
}